// Round 1
// baseline (704.888 us; speedup 1.0000x reference)
//
#include <hip/hip_runtime.h>
#include <math.h>

#define BDIM 4096
#define DDIM 256
#define NSTATE 9000000

__device__ __constant__ float c_ALPHA = 0.5f;
__device__ __constant__ float c_GAMMA_S = 0.8f;
__device__ __constant__ float c_GAMMA_U = 0.9f;
__device__ __constant__ float c_RHO = 6.0f;
__device__ __constant__ float c_EPS = 1e-14f;
__device__ __constant__ float c_ETA = 0.01f;
__device__ __constant__ float c_TAU_MIN = 0.001f;
__device__ __constant__ float c_TAU_MAX = 1.0f;
__device__ __constant__ float c_GRAD_CLIP = 5.0f;

// ---------- helpers ----------
__device__ inline unsigned encf(float f) {
    unsigned u = __float_as_uint(f);
    return (u & 0x80000000u) ? ~u : (u | 0x80000000u);
}
__device__ inline float decf(unsigned e) {
    return (e & 0x80000000u) ? __uint_as_float(e ^ 0x80000000u)
                             : __uint_as_float(~e);
}

// ---------- K1: row-normalize zis (rows 0..B-1) and zjs (rows B..2B-1) ----------
__global__ __launch_bounds__(256) void knorm(const float* __restrict__ zis,
                                             const float* __restrict__ zjs,
                                             float* __restrict__ zin,
                                             float* __restrict__ zjn) {
    int row = blockIdx.x;
    const float* src;
    float* dst;
    if (row < BDIM) { src = zis + (size_t)row * DDIM; dst = zin + (size_t)row * DDIM; }
    else            { src = zjs + (size_t)(row - BDIM) * DDIM; dst = zjn + (size_t)(row - BDIM) * DDIM; }
    int t = threadIdx.x;   // 256 == DDIM
    float v = src[t];
    __shared__ float red[256];
    red[t] = v * v;
    __syncthreads();
    for (int s = 128; s > 0; s >>= 1) {
        if (t < s) red[t] += red[t + s];
        __syncthreads();
    }
    float inv = rsqrtf(red[0]);
    dst[t] = v * inv;
}

// ---------- K2: fp32 NT GEMM: sim[i][j] = dot(zin[i,:], zjn[j,:]) ----------
#define BMT 128
#define BNT 128
#define BKT 16
__global__ __launch_bounds__(256) void kgemm(const float* __restrict__ A,
                                             const float* __restrict__ Bm,
                                             float* __restrict__ C) {
    __shared__ float As[BKT][BMT + 4];
    __shared__ float Bs[BKT][BNT + 4];
    int bx = blockIdx.x, by = blockIdx.y;
    int t = threadIdx.x;
    int tx = t & 15, ty = t >> 4;
    int m0 = by * BMT, n0 = bx * BNT;
    int kq = (t & 3) * 4;   // 0,4,8,12
    int lrow = t >> 2;      // 0..63

    float acc[8][8];
#pragma unroll
    for (int a = 0; a < 8; a++)
#pragma unroll
        for (int b = 0; b < 8; b++) acc[a][b] = 0.f;

    for (int k0 = 0; k0 < DDIM; k0 += BKT) {
        float4 a0 = *(const float4*)&A[(size_t)(m0 + lrow) * DDIM + k0 + kq];
        float4 a1 = *(const float4*)&A[(size_t)(m0 + lrow + 64) * DDIM + k0 + kq];
        float4 b0 = *(const float4*)&Bm[(size_t)(n0 + lrow) * DDIM + k0 + kq];
        float4 b1 = *(const float4*)&Bm[(size_t)(n0 + lrow + 64) * DDIM + k0 + kq];
        __syncthreads();
        As[kq + 0][lrow] = a0.x; As[kq + 1][lrow] = a0.y; As[kq + 2][lrow] = a0.z; As[kq + 3][lrow] = a0.w;
        As[kq + 0][lrow + 64] = a1.x; As[kq + 1][lrow + 64] = a1.y; As[kq + 2][lrow + 64] = a1.z; As[kq + 3][lrow + 64] = a1.w;
        Bs[kq + 0][lrow] = b0.x; Bs[kq + 1][lrow] = b0.y; Bs[kq + 2][lrow] = b0.z; Bs[kq + 3][lrow] = b0.w;
        Bs[kq + 0][lrow + 64] = b1.x; Bs[kq + 1][lrow + 64] = b1.y; Bs[kq + 2][lrow + 64] = b1.z; Bs[kq + 3][lrow + 64] = b1.w;
        __syncthreads();
#pragma unroll
        for (int k = 0; k < BKT; k++) {
            float4 t0 = *(const float4*)&As[k][ty * 4];
            float4 t1 = *(const float4*)&As[k][ty * 4 + 64];
            float4 t2 = *(const float4*)&Bs[k][tx * 4];
            float4 t3 = *(const float4*)&Bs[k][tx * 4 + 64];
            float am[8] = {t0.x, t0.y, t0.z, t0.w, t1.x, t1.y, t1.z, t1.w};
            float bn[8] = {t2.x, t2.y, t2.z, t2.w, t3.x, t3.y, t3.z, t3.w};
#pragma unroll
            for (int mi = 0; mi < 8; mi++)
#pragma unroll
                for (int ni = 0; ni < 8; ni++)
                    acc[mi][ni] = fmaf(am[mi], bn[ni], acc[mi][ni]);
        }
    }
#pragma unroll
    for (int mi = 0; mi < 8; mi++) {
        int m = m0 + ((mi < 4) ? (ty * 4 + mi) : (64 + ty * 4 + mi - 4));
        float4 v0 = make_float4(acc[mi][0], acc[mi][1], acc[mi][2], acc[mi][3]);
        float4 v1 = make_float4(acc[mi][4], acc[mi][5], acc[mi][6], acc[mi][7]);
        *(float4*)&C[(size_t)m * BDIM + n0 + tx * 4] = v0;
        *(float4*)&C[(size_t)m * BDIM + n0 + 64 + tx * 4] = v1;
    }
}

// ---------- K3a: per-row max + diag ----------
__global__ __launch_bounds__(256) void krowstats(const float* __restrict__ sim,
                                                 float* __restrict__ rowmax,
                                                 float* __restrict__ diag) {
    int i = blockIdx.x, t = threadIdx.x;
    float m = -INFINITY;
    for (int j = t; j < BDIM; j += 256) m = fmaxf(m, sim[(size_t)i * BDIM + j]);
    __shared__ float red[256];
    red[t] = m;
    __syncthreads();
    for (int s = 128; s > 0; s >>= 1) {
        if (t < s) red[t] = fmaxf(red[t], red[t + s]);
        __syncthreads();
    }
    if (t == 0) {
        rowmax[i] = red[0];
        diag[i] = sim[(size_t)i * BDIM + i];
    }
}

// ---------- K3b: per-col max (atomic on order-preserving uint encoding) ----------
__global__ __launch_bounds__(256) void kcolmax(const float* __restrict__ sim,
                                               unsigned* __restrict__ colmax_enc) {
    int j = blockIdx.x * 256 + threadIdx.x;
    int r0 = blockIdx.y * 128;
    float m = -INFINITY;
    for (int i = r0; i < r0 + 128; ++i) m = fmaxf(m, sim[(size_t)i * BDIM + j]);
    atomicMax(&colmax_enc[j], encf(m));
}

// ---------- K4: per-row pass: sums, state update values, outputs ----------
__global__ __launch_bounds__(256) void krowpass(const float* __restrict__ sim,
                                                const float* __restrict__ diag,
                                                const float* __restrict__ rowmax,
                                                const int* __restrict__ ids,
                                                const float* __restrict__ s_I,
                                                const float* __restrict__ b_I,
                                                const float* __restrict__ u_I,
                                                const float* __restrict__ tau_I,
                                                float* __restrict__ out_gi,
                                                float* __restrict__ out_grad,
                                                float* __restrict__ s_arr,
                                                float* __restrict__ b_arr,
                                                float* __restrict__ u_arr,
                                                float* __restrict__ tau_arr,
                                                float* __restrict__ img_loss_arr) {
    int i = blockIdx.x, t = threadIdx.x;
    int id = ids[i];
    float tau = tau_I[id];
    float oldb = b_I[id];
    float dg = diag[i];
    float inv_tau = 1.0f / tau;
    float newb = fmaxf(oldb, (rowmax[i] - dg) * inv_tau);
    float Asum = 0.f, Csum = 0.f;
    for (int j = t; j < BDIM; j += 256) {
        float d = sim[(size_t)i * BDIM + j] - dg;
        float e = __expf(d * inv_tau - newb);
        if (j == i) e = 0.f;
        Asum += e;
        Csum += e * d;
    }
    __shared__ float r1[256], r2[256];
    r1[t] = Asum; r2[t] = Csum;
    __syncthreads();
    for (int s = 128; s > 0; s >>= 1) {
        if (t < s) { r1[t] += r1[t + s]; r2[t] += r2[t + s]; }
        __syncthreads();
    }
    if (t == 0) {
        float g = r1[0], Cs = r2[0];
        float s_new = (1.f - c_GAMMA_S) * s_I[id] * __expf(oldb - newb) + c_GAMMA_S * g;
        float sc = fmaxf(s_new, c_EPS);
        float img_loss = Cs / sc;
        float grad = logf(sc) + newb + c_RHO - (Cs / (sc * tau)) / (float)(BDIM - 1);
        float gc = fminf(fmaxf(grad, -c_GRAD_CLIP), c_GRAD_CLIP);
        float u_new = (1.f - c_GAMMA_U) * u_I[id] + c_GAMMA_U * gc;
        float tau_new = fminf(fmaxf(tau - c_ETA * u_new, c_TAU_MIN), c_TAU_MAX);
        out_gi[i] = g;
        out_grad[i] = grad;
        s_arr[i] = s_new;
        b_arr[i] = newb;
        u_arr[i] = u_new;
        tau_arr[i] = tau_new;
        img_loss_arr[i] = img_loss;
    }
}

// ---------- K5: per-col partial sums ----------
__global__ __launch_bounds__(256) void kcolpartial(const float* __restrict__ sim,
                                                   const float* __restrict__ diag,
                                                   const unsigned* __restrict__ colmax_enc,
                                                   const int* __restrict__ ids,
                                                   const float* __restrict__ b_T,
                                                   const float* __restrict__ tau_T,
                                                   float* __restrict__ colA,
                                                   float* __restrict__ colC) {
    int j = blockIdx.x * 256 + threadIdx.x;
    int r0 = blockIdx.y * 128;
    int id = ids[j];
    float tau = tau_T[id];
    float dg = diag[j];
    float inv_tau = 1.0f / tau;
    float newb = fmaxf(b_T[id], (decf(colmax_enc[j]) - dg) * inv_tau);
    float Asum = 0.f, Csum = 0.f;
    for (int i = r0; i < r0 + 128; ++i) {
        float d = sim[(size_t)i * BDIM + j] - dg;
        float e = __expf(d * inv_tau - newb);
        if (i == j) e = 0.f;
        Asum += e;
        Csum += e * d;
    }
    atomicAdd(&colA[j], Asum);
    atomicAdd(&colC[j], Csum);
}

// ---------- K6: per-col finalize ----------
__global__ __launch_bounds__(256) void kcolfinal(const unsigned* __restrict__ colmax_enc,
                                                 const float* __restrict__ diag,
                                                 const int* __restrict__ ids,
                                                 const float* __restrict__ s_T,
                                                 const float* __restrict__ b_T,
                                                 const float* __restrict__ u_T,
                                                 const float* __restrict__ tau_T,
                                                 const float* __restrict__ colA,
                                                 const float* __restrict__ colC,
                                                 float* __restrict__ out_gt,
                                                 float* __restrict__ out_grad,
                                                 float* __restrict__ s_arr,
                                                 float* __restrict__ b_arr,
                                                 float* __restrict__ u_arr,
                                                 float* __restrict__ tau_arr,
                                                 float* __restrict__ txt_loss_arr) {
    int j = blockIdx.x * 256 + threadIdx.x;
    int id = ids[j];
    float tau = tau_T[id];
    float oldb = b_T[id];
    float dg = diag[j];
    float newb = fmaxf(oldb, (decf(colmax_enc[j]) - dg) / tau);
    float g = colA[j], Cs = colC[j];
    float s_new = (1.f - c_GAMMA_S) * s_T[id] * __expf(oldb - newb) + c_GAMMA_S * g;
    float sc = fmaxf(s_new, c_EPS);
    float txt_loss = Cs / sc;
    float grad = logf(sc) + newb + c_RHO - (Cs / (sc * tau)) / (float)(BDIM - 1);
    float gc = fminf(fmaxf(grad, -c_GRAD_CLIP), c_GRAD_CLIP);
    float u_new = (1.f - c_GAMMA_U) * u_T[id] + c_GAMMA_U * gc;
    float tau_new = fminf(fmaxf(tau - c_ETA * u_new, c_TAU_MIN), c_TAU_MAX);
    out_gt[j] = g;
    out_grad[j] = grad;
    s_arr[j] = s_new;
    b_arr[j] = newb;
    u_arr[j] = u_new;
    tau_arr[j] = tau_new;
    txt_loss_arr[j] = txt_loss;
}

// ---------- K7: final scalars ----------
__global__ __launch_bounds__(256) void kfinal(const float* __restrict__ img_loss_arr,
                                              const float* __restrict__ txt_loss_arr,
                                              const int* __restrict__ ids,
                                              const float* __restrict__ tau_I,
                                              const float* __restrict__ tau_T,
                                              float* __restrict__ O) {
    int t = threadIdx.x;
    float s0 = 0.f, s1 = 0.f, s2 = 0.f, s3 = 0.f;
    for (int k = t; k < BDIM; k += 256) {
        s0 += img_loss_arr[k];
        s1 += txt_loss_arr[k];
        int id = ids[k];
        s2 += tau_I[id];
        s3 += tau_T[id];
    }
    __shared__ float r0[256], r1[256], r2[256], r3[256];
    r0[t] = s0; r1[t] = s1; r2[t] = s2; r3[t] = s3;
    __syncthreads();
    for (int s = 128; s > 0; s >>= 1) {
        if (t < s) {
            r0[t] += r0[t + s]; r1[t] += r1[t + s];
            r2[t] += r2[t + s]; r3[t] += r3[t + s];
        }
        __syncthreads();
    }
    if (t == 0) {
        float invB = 1.0f / (float)BDIM;
        O[16384] = c_ALPHA * (r0[0] * invB) + (1.f - c_ALPHA) * (r1[0] * invB);
        O[16385] = r2[0] * invB;
        O[16386] = r3[0] * invB;
    }
}

// ---------- K8: bulk state copy (coalesced dword; dst only 4B-aligned) ----------
__global__ __launch_bounds__(256) void kcopy(const float* __restrict__ s_I,
                                             const float* __restrict__ s_T,
                                             const float* __restrict__ b_I,
                                             const float* __restrict__ b_T,
                                             const float* __restrict__ u_I,
                                             const float* __restrict__ u_T,
                                             const float* __restrict__ tau_I,
                                             const float* __restrict__ tau_T,
                                             float* __restrict__ o) {
    const float* srcs[8] = {s_I, s_T, b_I, b_T, u_I, u_T, tau_I, tau_T};
    long tid = (long)blockIdx.x * blockDim.x + threadIdx.x;
    long stride = (long)gridDim.x * blockDim.x;
#pragma unroll
    for (int b = 0; b < 8; b++) {
        const float* s = srcs[b];
        float* d = o + (long)b * NSTATE;
        for (long k = tid; k < NSTATE; k += stride) d[k] = s[k];
    }
}

// ---------- K9: scatter updated state at ids ----------
__global__ __launch_bounds__(256) void kscatter(const int* __restrict__ ids,
                                                const float* __restrict__ s_i_arr,
                                                const float* __restrict__ s_t_arr,
                                                const float* __restrict__ b_i_arr,
                                                const float* __restrict__ b_t_arr,
                                                const float* __restrict__ u_i_arr,
                                                const float* __restrict__ u_t_arr,
                                                const float* __restrict__ tau_i_arr,
                                                const float* __restrict__ tau_t_arr,
                                                float* __restrict__ o) {
    int t = blockIdx.x * 256 + threadIdx.x;
    if (t >= BDIM) return;
    long id = ids[t];
    o[0L * NSTATE + id] = s_i_arr[t];
    o[1L * NSTATE + id] = s_t_arr[t];
    o[2L * NSTATE + id] = b_i_arr[t];
    o[3L * NSTATE + id] = b_t_arr[t];
    o[4L * NSTATE + id] = u_i_arr[t];
    o[5L * NSTATE + id] = u_t_arr[t];
    o[6L * NSTATE + id] = tau_i_arr[t];
    o[7L * NSTATE + id] = tau_t_arr[t];
}

extern "C" void kernel_launch(void* const* d_in, const int* in_sizes, int n_in,
                              void* d_out, int out_size, void* d_ws, size_t ws_size,
                              hipStream_t stream) {
    const float* zis   = (const float*)d_in[0];
    const float* zjs   = (const float*)d_in[1];
    const int*   ids   = (const int*)d_in[2];
    const float* s_I   = (const float*)d_in[3];
    const float* s_T   = (const float*)d_in[4];
    const float* b_I   = (const float*)d_in[5];
    const float* b_T   = (const float*)d_in[6];
    const float* u_I   = (const float*)d_in[7];
    const float* u_T   = (const float*)d_in[8];
    const float* tau_I = (const float*)d_in[9];
    const float* tau_T = (const float*)d_in[10];
    float* O  = (float*)d_out;
    float* ws = (float*)d_ws;

    // scratch inside d_out's state region (overwritten by kcopy at the end).
    // offset 16388 + 4*NSTATE is =0 mod 4 floats -> 16B aligned for float4.
    size_t simoff = 16388 + 4ull * NSTATE;
    float* sim = O + simoff;
    float* zin = sim + 16777216;          // 4096*4096
    float* zjn = zin + (size_t)BDIM * DDIM;

    // d_ws small-array layout (floats)
    unsigned* colmax_enc = (unsigned*)ws;        // 4096 (zeroed)
    float* colA        = ws + 4096;              // zeroed
    float* colC        = ws + 8192;              // zeroed
    float* rowmax      = ws + 12288;
    float* diag        = ws + 16384;
    float* s_i_arr     = ws + 20480;
    float* b_i_arr     = ws + 24576;
    float* u_i_arr     = ws + 28672;
    float* tau_i_arr   = ws + 32768;
    float* s_t_arr     = ws + 36864;
    float* b_t_arr     = ws + 40960;
    float* u_t_arr     = ws + 45056;
    float* tau_t_arr   = ws + 49152;
    float* img_loss_arr = ws + 53248;
    float* txt_loss_arr = ws + 57344;

    hipMemsetAsync(d_ws, 0, 12288 * sizeof(float), stream);

    knorm<<<2 * BDIM, 256, 0, stream>>>(zis, zjs, zin, zjn);
    kgemm<<<dim3(BDIM / BNT, BDIM / BMT), 256, 0, stream>>>(zin, zjn, sim);
    krowstats<<<BDIM, 256, 0, stream>>>(sim, rowmax, diag);
    kcolmax<<<dim3(BDIM / 256, 32), 256, 0, stream>>>(sim, colmax_enc);
    krowpass<<<BDIM, 256, 0, stream>>>(sim, diag, rowmax, ids, s_I, b_I, u_I, tau_I,
                                       O, O + 8192,
                                       s_i_arr, b_i_arr, u_i_arr, tau_i_arr, img_loss_arr);
    kcolpartial<<<dim3(BDIM / 256, 32), 256, 0, stream>>>(sim, diag, colmax_enc, ids, b_T, tau_T,
                                                          colA, colC);
    kcolfinal<<<BDIM / 256, 256, 0, stream>>>(colmax_enc, diag, ids, s_T, b_T, u_T, tau_T,
                                              colA, colC,
                                              O + 4096, O + 12288,
                                              s_t_arr, b_t_arr, u_t_arr, tau_t_arr, txt_loss_arr);
    kfinal<<<1, 256, 0, stream>>>(img_loss_arr, txt_loss_arr, ids, tau_I, tau_T, O);
    kcopy<<<8192, 256, 0, stream>>>(s_I, s_T, b_I, b_T, u_I, u_T, tau_I, tau_T, O + 16387);
    kscatter<<<BDIM / 256, 256, 0, stream>>>(ids, s_i_arr, s_t_arr, b_i_arr, b_t_arr,
                                             u_i_arr, u_t_arr, tau_i_arr, tau_t_arr, O + 16387);
}